// Round 3
// baseline (17748.695 us; speedup 1.0000x reference)
//
#include <hip/hip_runtime.h>
#include <math.h>

#define NS 512
#define NE 2048
#define NB 64
#define NT 512

// out[c][r] = in[r][c]; rows, cols multiples of 32
__global__ __launch_bounds__(256) void transpose_k(const float* __restrict__ in,
                                                   float* __restrict__ out,
                                                   int rows, int cols) {
  __shared__ float tile[32][33];
  int c0 = blockIdx.x * 32;
  int r0 = blockIdx.y * 32;
  int tx = threadIdx.x;  // 0..31
  int ty = threadIdx.y;  // 0..7
#pragma unroll
  for (int k = 0; k < 32; k += 8) {
    tile[ty + k][tx] = in[(size_t)(r0 + ty + k) * cols + (c0 + tx)];
  }
  __syncthreads();
#pragma unroll
  for (int k = 0; k < 32; k += 8) {
    out[(size_t)(c0 + ty + k) * rows + (r0 + tx)] = tile[tx][ty + k];
  }
}

// Forward: one block per batch, 1024 threads, trans held in registers.
// Thread (j = tid&511, h = tid>>9) owns T[i in h*256..h*256+255][j] as 64 float4s.
__global__ __launch_bounds__(1024, 4) void viterbi_fwd(
    const int* __restrict__ obs,     // [NB][NT]
    const float* __restrict__ start, // [NS]
    const float* __restrict__ trans, // [NS][NS]
    const float* __restrict__ emT,   // [NE][NS]
    float* __restrict__ v)           // [NT][NB][NS]
{
  const int b = blockIdx.x;
  const int tid = threadIdx.x;
  const int j = tid & (NS - 1);
  const int h = tid >> 9;  // 0 or 1 (wave-uniform)
  const int ibase = h * 256;

  __shared__ __align__(16) float vcur[NS];
  __shared__ float part[NS];
  __shared__ int obs_s[NT];

  if (tid < NT) obs_s[tid] = obs[b * NT + tid];

  // Load my trans column-slice into registers (coalesced: lane -> j).
  float4 tj[64];
#pragma unroll
  for (int c = 0; c < 64; ++c) {
    const float* p = trans + (size_t)(ibase + c * 4) * NS + j;
    tj[c].x = p[0 * NS];
    tj[c].y = p[1 * NS];
    tj[c].z = p[2 * NS];
    tj[c].w = p[3 * NS];
  }

  // t = 0 (h==0 half computes)
  if (h == 0) {
    float vj = start[j] + emT[(size_t)obs[b * NT] * NS + j];
    vcur[j] = vj;
    v[((size_t)0 * NB + b) * NS + j] = vj;
  }
  __syncthreads();

  float e_next = (h == 0) ? emT[(size_t)obs_s[1] * NS + j] : 0.0f;

  for (int t = 1; t < NT; ++t) {
    float e_cur = e_next;
    if (h == 0 && t + 1 < NT) e_next = emT[(size_t)obs_s[t + 1] * NS + j];

    float m0 = -INFINITY, m1 = -INFINITY, m2 = -INFINITY, m3 = -INFINITY;
#pragma unroll
    for (int c = 0; c < 64; ++c) {
      // wave-uniform address -> LDS broadcast read, conflict-free
      float4 vv = *reinterpret_cast<const float4*>(&vcur[ibase + c * 4]);
      float s0 = vv.x + tj[c].x;
      float s1 = vv.y + tj[c].y;
      float s2 = vv.z + tj[c].z;
      float s3 = vv.w + tj[c].w;
      m0 = fmaxf(m0, fmaxf(s0, s1));  // v_max3
      m1 = fmaxf(m1, fmaxf(s2, s3));
    }
    float m = fmaxf(fmaxf(m0, m1), fmaxf(m2, m3));

    if (h == 1) part[j] = m;
    __syncthreads();  // vcur reads done + part visible
    if (h == 0) {
      m = fmaxf(m, part[j]);
      float vn = m + e_cur;
      vcur[j] = vn;
      v[((size_t)t * NB + b) * NS + j] = vn;
    }
    __syncthreads();
  }
}

// Backtrace: one wave per batch; recompute argmax with exact first-wins ties.
// v[t-1] row is prefetched one step ahead (state-independent); only the
// transT[state] row sits on the dependent chain.
__global__ __launch_bounds__(64) void viterbi_bt(
    const float* __restrict__ v,      // [NT][NB][NS]
    const float* __restrict__ transT, // [NS][NS], transT[j][i] = trans[i][j]
    int* __restrict__ path)           // [NB][NT] int32
{
  const int b = blockIdx.x;
  const int lane = threadIdx.x;

  // argmax over final v row (first index wins): lane covers idx 4*lane..4*lane+3, 4*(lane+64)..
  const float4* vrow = reinterpret_cast<const float4*>(v + ((size_t)(NT - 1) * NB + b) * NS);
  float val = -INFINITY;
  int idx = 0;
#pragma unroll
  for (int w = 0; w < 2; ++w) {
    float4 a = vrow[lane + 64 * w];
    int base = 4 * (lane + 64 * w);
    if (a.x > val) { val = a.x; idx = base + 0; }
    if (a.y > val) { val = a.y; idx = base + 1; }
    if (a.z > val) { val = a.z; idx = base + 2; }
    if (a.w > val) { val = a.w; idx = base + 3; }
  }
#pragma unroll
  for (int off = 32; off; off >>= 1) {
    float v2 = __shfl_down(val, off);
    int i2 = __shfl_down(idx, off);
    if (v2 > val || (v2 == val && i2 < idx)) { val = v2; idx = i2; }
  }
  int state = __shfl(idx, 0);
  if (lane == 0) path[b * NT + (NT - 1)] = state;

  // prefetch v[T-2] row
  float4 vp0, vp1;
  {
    const float4* vp = reinterpret_cast<const float4*>(v + ((size_t)(NT - 2) * NB + b) * NS);
    vp0 = vp[lane];
    vp1 = vp[lane + 64];
  }

  for (int t = NT - 1; t >= 1; --t) {
    // issue next prefetch first (independent of state)
    float4 np0, np1;
    if (t >= 2) {
      const float4* vp = reinterpret_cast<const float4*>(v + ((size_t)(t - 2) * NB + b) * NS);
      np0 = vp[lane];
      np1 = vp[lane + 64];
    }
    const float4* tr = reinterpret_cast<const float4*>(transT + (size_t)state * NS);
    float4 t0 = tr[lane];
    float4 t1 = tr[lane + 64];

    float val2 = -INFINITY;
    int idx2 = 0;
    {
      float s0 = vp0.x + t0.x, s1 = vp0.y + t0.y, s2 = vp0.z + t0.z, s3 = vp0.w + t0.w;
      int base = 4 * lane;
      if (s0 > val2) { val2 = s0; idx2 = base + 0; }
      if (s1 > val2) { val2 = s1; idx2 = base + 1; }
      if (s2 > val2) { val2 = s2; idx2 = base + 2; }
      if (s3 > val2) { val2 = s3; idx2 = base + 3; }
    }
    {
      float s0 = vp1.x + t1.x, s1 = vp1.y + t1.y, s2 = vp1.z + t1.z, s3 = vp1.w + t1.w;
      int base = 4 * (lane + 64);
      if (s0 > val2) { val2 = s0; idx2 = base + 0; }
      if (s1 > val2) { val2 = s1; idx2 = base + 1; }
      if (s2 > val2) { val2 = s2; idx2 = base + 2; }
      if (s3 > val2) { val2 = s3; idx2 = base + 3; }
    }
#pragma unroll
    for (int off = 32; off; off >>= 1) {
      float v2 = __shfl_down(val2, off);
      int i2 = __shfl_down(idx2, off);
      if (v2 > val2 || (v2 == val2 && i2 < idx2)) { val2 = v2; idx2 = i2; }
    }
    state = __shfl(idx2, 0);
    if (lane == 0) path[b * NT + (t - 1)] = state;
    vp0 = np0;
    vp1 = np1;
  }
}

extern "C" void kernel_launch(void* const* d_in, const int* in_sizes, int n_in,
                              void* d_out, int out_size, void* d_ws, size_t ws_size,
                              hipStream_t stream) {
  const int* obs = (const int*)d_in[0];       // [64][512]
  const float* start = (const float*)d_in[1]; // [512]
  const float* trans = (const float*)d_in[2]; // [512][512]
  const float* emis = (const float*)d_in[3];  // [512][2048]
  int* path = (int*)d_out;                    // [64][512] int32

  char* ws = (char*)d_ws;
  float* emT = (float*)ws;                          // [2048][512] = 4 MB
  float* transT = (float*)(ws + (4u << 20));        // [512][512]  = 1 MB
  float* v = (float*)(ws + (5u << 20));             // [512][64][512] = 64 MB

  dim3 tb(32, 8);
  transpose_k<<<dim3(NE / 32, NS / 32), tb, 0, stream>>>(emis, emT, NS, NE);
  transpose_k<<<dim3(NS / 32, NS / 32), tb, 0, stream>>>(trans, transT, NS, NS);
  viterbi_fwd<<<NB, 1024, 0, stream>>>(obs, start, trans, emT, v);
  viterbi_bt<<<NB, 64, 0, stream>>>(v, transT, path);
}

// Round 4
// 15391.901 us; speedup vs baseline: 1.1531x; 1.1531x over previous
//
#include <hip/hip_runtime.h>
#include <math.h>

#define NS 512
#define NE 2048
#define NB 64
#define NT 512

// out[c][r] = in[r][c]; rows, cols multiples of 32
__global__ __launch_bounds__(256) void transpose_k(const float* __restrict__ in,
                                                   float* __restrict__ out,
                                                   int rows, int cols) {
  __shared__ float tile[32][33];
  int c0 = blockIdx.x * 32;
  int r0 = blockIdx.y * 32;
  int tx = threadIdx.x;  // 0..31
  int ty = threadIdx.y;  // 0..7
#pragma unroll
  for (int k = 0; k < 32; k += 8) {
    tile[ty + k][tx] = in[(size_t)(r0 + ty + k) * cols + (c0 + tx)];
  }
  __syncthreads();
#pragma unroll
  for (int k = 0; k < 32; k += 8) {
    out[(size_t)(c0 + ty + k) * rows + (r0 + tx)] = tile[tx][ty + k];
  }
}

// 64 macro repetitions with literal indices -> 64 NAMED float4 variables,
// no alloca, nothing the compiler can demote to scratch.
#define REP64(M) \
  M(0) M(1) M(2) M(3) M(4) M(5) M(6) M(7) \
  M(8) M(9) M(10) M(11) M(12) M(13) M(14) M(15) \
  M(16) M(17) M(18) M(19) M(20) M(21) M(22) M(23) \
  M(24) M(25) M(26) M(27) M(28) M(29) M(30) M(31) \
  M(32) M(33) M(34) M(35) M(36) M(37) M(38) M(39) \
  M(40) M(41) M(42) M(43) M(44) M(45) M(46) M(47) \
  M(48) M(49) M(50) M(51) M(52) M(53) M(54) M(55) \
  M(56) M(57) M(58) M(59) M(60) M(61) M(62) M(63)

// Forward: one block per batch, 1024 threads, trans held in registers.
// Thread (j = tid&511, h = tid>>9) owns T[i in h*256..h*256+255][j] as t0..t63.
__global__ __launch_bounds__(1024, 4) void viterbi_fwd(
    const int* __restrict__ obs,     // [NB][NT]
    const float* __restrict__ start, // [NS]
    const float* __restrict__ trans, // [NS][NS]
    const float* __restrict__ emT,   // [NE][NS]
    float* __restrict__ v)           // [NT][NB][NS]
{
  const int b = blockIdx.x;
  const int tid = threadIdx.x;
  const int j = tid & (NS - 1);
  const int h = tid >> 9;  // 0 or 1 (wave-uniform)
  const int ibase = h * 256;

  __shared__ __align__(16) float vcur[NS];
  __shared__ float part[NS];
  __shared__ int obs_s[NT];

  if (tid < NT) obs_s[tid] = obs[b * NT + tid];

  // Load my trans column-slice into 64 named float4 registers (coalesced in j).
#define LOADT(c) \
  float4 t##c; \
  { const float* p = trans + (size_t)(ibase + (c) * 4) * NS + j; \
    t##c.x = p[0 * NS]; t##c.y = p[1 * NS]; t##c.z = p[2 * NS]; t##c.w = p[3 * NS]; }
  REP64(LOADT)
#undef LOADT

  // t = 0 (h==0 half computes)
  if (h == 0) {
    float vj = start[j] + emT[(size_t)obs[b * NT] * NS + j];
    vcur[j] = vj;
    v[((size_t)0 * NB + b) * NS + j] = vj;
  }
  __syncthreads();

  const float4* vc4 = reinterpret_cast<const float4*>(vcur + ibase);
  float e_next = (h == 0) ? emT[(size_t)obs_s[1] * NS + j] : 0.0f;

  for (int t = 1; t < NT; ++t) {
    float e_cur = e_next;
    if (h == 0 && t + 1 < NT) e_next = emT[(size_t)obs_s[t + 1] * NS + j];

    float m0 = -INFINITY, m1 = -INFINITY;
    // wave-uniform LDS broadcast reads + register trans: 4 add + 2 max3 per c
#define STEPC(c) \
    { float4 vv = vc4[c]; \
      m0 = fmaxf(m0, fmaxf(vv.x + t##c.x, vv.y + t##c.y)); \
      m1 = fmaxf(m1, fmaxf(vv.z + t##c.z, vv.w + t##c.w)); }
    REP64(STEPC)
#undef STEPC
    float m = fmaxf(m0, m1);

    if (h == 1) part[j] = m;
    __syncthreads();  // vcur reads done + part visible
    if (h == 0) {
      m = fmaxf(m, part[j]);
      float vn = m + e_cur;
      vcur[j] = vn;
      v[((size_t)t * NB + b) * NS + j] = vn;
    }
    __syncthreads();
  }
}

// Backtrace: one wave per batch; recompute argmax with exact first-wins ties.
// v[t-1] row is prefetched one step ahead (state-independent); only the
// transT[state] row sits on the dependent chain.
__global__ __launch_bounds__(64) void viterbi_bt(
    const float* __restrict__ v,      // [NT][NB][NS]
    const float* __restrict__ transT, // [NS][NS], transT[j][i] = trans[i][j]
    int* __restrict__ path)           // [NB][NT] int32
{
  const int b = blockIdx.x;
  const int lane = threadIdx.x;

  // argmax over final v row (first index wins): lane covers idx 4*lane..4*lane+3, ...
  const float4* vrow = reinterpret_cast<const float4*>(v + ((size_t)(NT - 1) * NB + b) * NS);
  float val = -INFINITY;
  int idx = 0;
#pragma unroll
  for (int w = 0; w < 2; ++w) {
    float4 a = vrow[lane + 64 * w];
    int base = 4 * (lane + 64 * w);
    if (a.x > val) { val = a.x; idx = base + 0; }
    if (a.y > val) { val = a.y; idx = base + 1; }
    if (a.z > val) { val = a.z; idx = base + 2; }
    if (a.w > val) { val = a.w; idx = base + 3; }
  }
#pragma unroll
  for (int off = 32; off; off >>= 1) {
    float v2 = __shfl_down(val, off);
    int i2 = __shfl_down(idx, off);
    if (v2 > val || (v2 == val && i2 < idx)) { val = v2; idx = i2; }
  }
  int state = __shfl(idx, 0);
  if (lane == 0) path[b * NT + (NT - 1)] = state;

  // prefetch v[T-2] row
  float4 vp0, vp1;
  {
    const float4* vp = reinterpret_cast<const float4*>(v + ((size_t)(NT - 2) * NB + b) * NS);
    vp0 = vp[lane];
    vp1 = vp[lane + 64];
  }

  for (int t = NT - 1; t >= 1; --t) {
    // issue next prefetch first (independent of state)
    float4 np0, np1;
    if (t >= 2) {
      const float4* vp = reinterpret_cast<const float4*>(v + ((size_t)(t - 2) * NB + b) * NS);
      np0 = vp[lane];
      np1 = vp[lane + 64];
    }
    const float4* tr = reinterpret_cast<const float4*>(transT + (size_t)state * NS);
    float4 t0 = tr[lane];
    float4 t1 = tr[lane + 64];

    float val2 = -INFINITY;
    int idx2 = 0;
    {
      float s0 = vp0.x + t0.x, s1 = vp0.y + t0.y, s2 = vp0.z + t0.z, s3 = vp0.w + t0.w;
      int base = 4 * lane;
      if (s0 > val2) { val2 = s0; idx2 = base + 0; }
      if (s1 > val2) { val2 = s1; idx2 = base + 1; }
      if (s2 > val2) { val2 = s2; idx2 = base + 2; }
      if (s3 > val2) { val2 = s3; idx2 = base + 3; }
    }
    {
      float s0 = vp1.x + t1.x, s1 = vp1.y + t1.y, s2 = vp1.z + t1.z, s3 = vp1.w + t1.w;
      int base = 4 * (lane + 64);
      if (s0 > val2) { val2 = s0; idx2 = base + 0; }
      if (s1 > val2) { val2 = s1; idx2 = base + 1; }
      if (s2 > val2) { val2 = s2; idx2 = base + 2; }
      if (s3 > val2) { val2 = s3; idx2 = base + 3; }
    }
#pragma unroll
    for (int off = 32; off; off >>= 1) {
      float v2 = __shfl_down(val2, off);
      int i2 = __shfl_down(idx2, off);
      if (v2 > val2 || (v2 == val2 && i2 < idx2)) { val2 = v2; idx2 = i2; }
    }
    state = __shfl(idx2, 0);
    if (lane == 0) path[b * NT + (t - 1)] = state;
    vp0 = np0;
    vp1 = np1;
  }
}

extern "C" void kernel_launch(void* const* d_in, const int* in_sizes, int n_in,
                              void* d_out, int out_size, void* d_ws, size_t ws_size,
                              hipStream_t stream) {
  const int* obs = (const int*)d_in[0];       // [64][512]
  const float* start = (const float*)d_in[1]; // [512]
  const float* trans = (const float*)d_in[2]; // [512][512]
  const float* emis = (const float*)d_in[3];  // [512][2048]
  int* path = (int*)d_out;                    // [64][512] int32

  char* ws = (char*)d_ws;
  float* emT = (float*)ws;                          // [2048][512] = 4 MB
  float* transT = (float*)(ws + (4u << 20));        // [512][512]  = 1 MB
  float* v = (float*)(ws + (5u << 20));             // [512][64][512] = 64 MB

  dim3 tb(32, 8);
  transpose_k<<<dim3(NE / 32, NS / 32), tb, 0, stream>>>(emis, emT, NS, NE);
  transpose_k<<<dim3(NS / 32, NS / 32), tb, 0, stream>>>(trans, transT, NS, NS);
  viterbi_fwd<<<NB, 1024, 0, stream>>>(obs, start, trans, emT, v);
  viterbi_bt<<<NB, 64, 0, stream>>>(v, transT, path);
}

// Round 5
// 2954.097 us; speedup vs baseline: 6.0082x; 5.2104x over previous
//
#include <hip/hip_runtime.h>
#include <math.h>

#define NS 512
#define NE 2048
#define NB 64
#define NT 512

// out[c][r] = in[r][c]; rows, cols multiples of 32
__global__ __launch_bounds__(256) void transpose_k(const float* __restrict__ in,
                                                   float* __restrict__ out,
                                                   int rows, int cols) {
  __shared__ float tile[32][33];
  int c0 = blockIdx.x * 32;
  int r0 = blockIdx.y * 32;
  int tx = threadIdx.x;  // 0..31
  int ty = threadIdx.y;  // 0..7
#pragma unroll
  for (int k = 0; k < 32; k += 8) {
    tile[ty + k][tx] = in[(size_t)(r0 + ty + k) * cols + (c0 + tx)];
  }
  __syncthreads();
#pragma unroll
  for (int k = 0; k < 32; k += 8) {
    out[(size_t)(c0 + ty + k) * rows + (r0 + tx)] = tile[tx][ty + k];
  }
}

#define REP32(M) \
  M(0) M(1) M(2) M(3) M(4) M(5) M(6) M(7) \
  M(8) M(9) M(10) M(11) M(12) M(13) M(14) M(15) \
  M(16) M(17) M(18) M(19) M(20) M(21) M(22) M(23) \
  M(24) M(25) M(26) M(27) M(28) M(29) M(30) M(31)

// Forward, trans-stationary: 4 blocks per batch. Block member m (0..3) of group g
// holds T[i in 128m..128m+127][j] in registers (thread j: 32 float4 = 128 VGPR).
// Per step: local partial max over the i-slice, then 4-way exchange via
// agent-scope atomics (IC coherence point) + monotonic flag counter.
// Blocks {g, g+64, g+128, g+192} form group g (same XCD residue mod 8).
__global__ __launch_bounds__(512, 2) void viterbi_fwd(
    const int* __restrict__ obs,     // [NB][NT]
    const float* __restrict__ start, // [NS]
    const float* __restrict__ trans, // [NS][NS]
    const float* __restrict__ emT,   // [NE][NS]
    float* __restrict__ v,           // [NT][NB][NS]
    float* __restrict__ partials,    // [2][NB][4][NS]
    int* __restrict__ flags)         // [NB][32], zeroed before launch
{
  const int g = blockIdx.x & 63;   // batch / group
  const int m = blockIdx.x >> 6;   // member 0..3
  const int j = threadIdx.x;       // 0..511
  const int i0 = m * 128;

  __shared__ __align__(16) float vcur[NS];
  __shared__ int obs_s[NT];

  obs_s[j] = obs[g * NT + j];

  // T[i0 + 4c + r][j] -> t{c}.{x,y,z,w}; named vars, literal indices: must stay in VGPRs.
#define LOADT(c) \
  float4 t##c; \
  { const float* p = trans + (size_t)(i0 + (c) * 4) * NS + j; \
    t##c.x = p[0 * NS]; t##c.y = p[1 * NS]; t##c.z = p[2 * NS]; t##c.w = p[3 * NS]; }
  REP32(LOADT)
#undef LOADT

  __syncthreads();
  // t = 0 (every member computes identically; member 0 checkpoints)
  float vj = start[j] + emT[(size_t)obs_s[0] * NS + j];
  vcur[j] = vj;
  if (m == 0) v[((size_t)0 * NB + g) * NS + j] = vj;
  __syncthreads();

  float e_next = emT[(size_t)obs_s[1] * NS + j];
  int* flag = flags + g * 32;

  for (int t = 1; t < NT; ++t) {
    float e_cur = e_next;
    if (t + 1 < NT) e_next = emT[(size_t)obs_s[t + 1] * NS + j];

    // partial_m[j] = max over my 128-row i-slice
    float m0 = -INFINITY, m1 = -INFINITY;
    const float4* vc4 = reinterpret_cast<const float4*>(vcur + i0);
#define STEPC(c) \
    { float4 vv = vc4[c]; \
      m0 = fmaxf(m0, fmaxf(vv.x + t##c.x, vv.y + t##c.y)); \
      m1 = fmaxf(m1, fmaxf(vv.z + t##c.z, vv.w + t##c.w)); }
    REP32(STEPC)
#undef STEPC
    float pm = fmaxf(m0, m1);

    // publish my partial (write-through to coherence point)
    float* pbase = partials + (((size_t)(t & 1) * NB + g) * 4) * NS;
    __hip_atomic_store(pbase + m * NS + j, pm, __ATOMIC_RELAXED, __HIP_MEMORY_SCOPE_AGENT);
    __syncthreads();  // all vcur reads done; all partial stores drained (vmcnt 0)

    if (j == 0) {
      __hip_atomic_fetch_add(flag, 1, __ATOMIC_RELEASE, __HIP_MEMORY_SCOPE_AGENT);
      const int target = 4 * t;
      while (__hip_atomic_load(flag, __ATOMIC_RELAXED, __HIP_MEMORY_SCOPE_AGENT) < target) {
        __builtin_amdgcn_s_sleep(2);
      }
      (void)__hip_atomic_load(flag, __ATOMIC_ACQUIRE, __HIP_MEMORY_SCOPE_AGENT);
    }
    __syncthreads();  // flag observed -> all 4 partials are at the coherence point

    float q1 = __hip_atomic_load(pbase + (((m + 1) & 3) * NS) + j, __ATOMIC_RELAXED, __HIP_MEMORY_SCOPE_AGENT);
    float q2 = __hip_atomic_load(pbase + (((m + 2) & 3) * NS) + j, __ATOMIC_RELAXED, __HIP_MEMORY_SCOPE_AGENT);
    float q3 = __hip_atomic_load(pbase + (((m + 3) & 3) * NS) + j, __ATOMIC_RELAXED, __HIP_MEMORY_SCOPE_AGENT);
    float vn = fmaxf(fmaxf(pm, q1), fmaxf(q2, q3)) + e_cur;

    vcur[j] = vn;  // safe: all reads of old vcur happened before first barrier
    if (m == 0) v[((size_t)t * NB + g) * NS + j] = vn;
    __syncthreads();
  }
}

// Backtrace: one wave per batch; recompute argmax with exact first-wins ties.
__global__ __launch_bounds__(64) void viterbi_bt(
    const float* __restrict__ v,      // [NT][NB][NS]
    const float* __restrict__ transT, // [NS][NS], transT[j][i] = trans[i][j]
    int* __restrict__ path)           // [NB][NT] int32
{
  const int b = blockIdx.x;
  const int lane = threadIdx.x;

  const float4* vrow = reinterpret_cast<const float4*>(v + ((size_t)(NT - 1) * NB + b) * NS);
  float val = -INFINITY;
  int idx = 0;
#pragma unroll
  for (int w = 0; w < 2; ++w) {
    float4 a = vrow[lane + 64 * w];
    int base = 4 * (lane + 64 * w);
    if (a.x > val) { val = a.x; idx = base + 0; }
    if (a.y > val) { val = a.y; idx = base + 1; }
    if (a.z > val) { val = a.z; idx = base + 2; }
    if (a.w > val) { val = a.w; idx = base + 3; }
  }
#pragma unroll
  for (int off = 32; off; off >>= 1) {
    float v2 = __shfl_down(val, off);
    int i2 = __shfl_down(idx, off);
    if (v2 > val || (v2 == val && i2 < idx)) { val = v2; idx = i2; }
  }
  int state = __shfl(idx, 0);
  if (lane == 0) path[b * NT + (NT - 1)] = state;

  float4 vp0, vp1;
  {
    const float4* vp = reinterpret_cast<const float4*>(v + ((size_t)(NT - 2) * NB + b) * NS);
    vp0 = vp[lane];
    vp1 = vp[lane + 64];
  }

  for (int t = NT - 1; t >= 1; --t) {
    float4 np0, np1;
    if (t >= 2) {
      const float4* vp = reinterpret_cast<const float4*>(v + ((size_t)(t - 2) * NB + b) * NS);
      np0 = vp[lane];
      np1 = vp[lane + 64];
    }
    const float4* tr = reinterpret_cast<const float4*>(transT + (size_t)state * NS);
    float4 t0 = tr[lane];
    float4 t1 = tr[lane + 64];

    float val2 = -INFINITY;
    int idx2 = 0;
    {
      float s0 = vp0.x + t0.x, s1 = vp0.y + t0.y, s2 = vp0.z + t0.z, s3 = vp0.w + t0.w;
      int base = 4 * lane;
      if (s0 > val2) { val2 = s0; idx2 = base + 0; }
      if (s1 > val2) { val2 = s1; idx2 = base + 1; }
      if (s2 > val2) { val2 = s2; idx2 = base + 2; }
      if (s3 > val2) { val2 = s3; idx2 = base + 3; }
    }
    {
      float s0 = vp1.x + t1.x, s1 = vp1.y + t1.y, s2 = vp1.z + t1.z, s3 = vp1.w + t1.w;
      int base = 4 * (lane + 64);
      if (s0 > val2) { val2 = s0; idx2 = base + 0; }
      if (s1 > val2) { val2 = s1; idx2 = base + 1; }
      if (s2 > val2) { val2 = s2; idx2 = base + 2; }
      if (s3 > val2) { val2 = s3; idx2 = base + 3; }
    }
#pragma unroll
    for (int off = 32; off; off >>= 1) {
      float v2 = __shfl_down(val2, off);
      int i2 = __shfl_down(idx2, off);
      if (v2 > val2 || (v2 == val2 && i2 < idx2)) { val2 = v2; idx2 = i2; }
    }
    state = __shfl(idx2, 0);
    if (lane == 0) path[b * NT + (t - 1)] = state;
    vp0 = np0;
    vp1 = np1;
  }
}

extern "C" void kernel_launch(void* const* d_in, const int* in_sizes, int n_in,
                              void* d_out, int out_size, void* d_ws, size_t ws_size,
                              hipStream_t stream) {
  const int* obs = (const int*)d_in[0];       // [64][512]
  const float* start = (const float*)d_in[1]; // [512]
  const float* trans = (const float*)d_in[2]; // [512][512]
  const float* emis = (const float*)d_in[3];  // [512][2048]
  int* path = (int*)d_out;                    // [64][512] int32

  char* ws = (char*)d_ws;
  float* emT = (float*)ws;                           // [2048][512] = 4 MB
  float* transT = (float*)(ws + (4ull << 20));       // [512][512]  = 1 MB
  float* v = (float*)(ws + (5ull << 20));            // [512][64][512] = 64 MB
  float* partials = (float*)(ws + (69ull << 20));    // [2][64][4][512] = 1 MB
  int* flags = (int*)(ws + (70ull << 20));           // [64][32] = 8 KB

  hipMemsetAsync(flags, 0, NB * 32 * sizeof(int), stream);

  dim3 tb(32, 8);
  transpose_k<<<dim3(NE / 32, NS / 32), tb, 0, stream>>>(emis, emT, NS, NE);
  transpose_k<<<dim3(NS / 32, NS / 32), tb, 0, stream>>>(trans, transT, NS, NS);
  viterbi_fwd<<<NB * 4, 512, 0, stream>>>(obs, start, trans, emT, v, partials, flags);
  viterbi_bt<<<NB, 64, 0, stream>>>(v, transT, path);
}